// Round 1
// baseline (327.023 us; speedup 1.0000x reference)
//
#include <hip/hip_runtime.h>
#include <cstdint>

#define Bsz 2
#define Lsz 2048
#define Dm  512
#define Nst 64
#define Rr  32
#define Ee  160   // r + 2n

// ---------------- K1: x_dbl = x @ W_xproj^T  (4096 x 160) ----------------
__global__ __launch_bounds__(256) void k1_xproj(const float* __restrict__ x,
                                                const float* __restrict__ W,
                                                float* __restrict__ xdbl) {
    __shared__ float xs[16][516];   // 16 rows of x, padded (516%32=4 -> 2-way, free)
    const int tid = threadIdx.x;
    const int row0 = blockIdx.x * 16;
    // stage 16x512 x-tile, coalesced float4
    for (int i = tid; i < 16 * 128; i += 256) {
        int r = i >> 7, c4 = i & 127;
        const float4 v = *reinterpret_cast<const float4*>(x + (size_t)(row0 + r) * Dm + c4 * 4);
        *reinterpret_cast<float4*>(&xs[r][c4 * 4]) = v;
    }
    __syncthreads();
    // 16*160 = 2560 outputs, 10 per thread
    for (int oi = tid; oi < 16 * Ee; oi += 256) {
        int r = oi / Ee, e = oi - r * Ee;
        const float4* wr = reinterpret_cast<const float4*>(W + (size_t)e * Dm);
        const float4* xr = reinterpret_cast<const float4*>(&xs[r][0]);
        float acc = 0.f;
        #pragma unroll 8
        for (int k = 0; k < 128; ++k) {
            float4 a = xr[k]; float4 w = wr[k];
            acc = fmaf(a.x, w.x, acc); acc = fmaf(a.y, w.y, acc);
            acc = fmaf(a.z, w.z, acc); acc = fmaf(a.w, w.w, acc);
        }
        xdbl[(size_t)(row0 + r) * Ee + e] = acc;
    }
}

// ------- K2: delta = softplus(delta_r @ W_dt^T + b_dt); store delta,
//             du = delta*x transposed to (b, d, l) with coalesced writes -------
__global__ __launch_bounds__(256) void k2_delta(const float* __restrict__ xdbl,
                                                const float* __restrict__ x,
                                                const float* __restrict__ Wdt,
                                                const float* __restrict__ bdt,
                                                float* __restrict__ delta_t,
                                                float* __restrict__ du_t) {
    __shared__ float dr[64][33];   // delta_r tile (l, r) padded -> conflict-free lane reads
    __shared__ float wd[64][32];   // W_dt tile (d, r), read broadcast
    __shared__ float pt[64][65];   // transpose buffer (d, l)
    const int tid = threadIdx.x;
    const int lt = blockIdx.x & 31;
    const int dt = (blockIdx.x >> 5) & 7;
    const int b  = blockIdx.x >> 8;
    const int l0 = lt * 64, d0 = dt * 64;

    for (int i = tid; i < 512; i += 256) {          // 64 rows x 8 float4
        int l = i >> 3, j4 = i & 7;
        const float4 v = *reinterpret_cast<const float4*>(
            xdbl + (size_t)(b * Lsz + l0 + l) * Ee + j4 * 4);
        dr[l][j4 * 4 + 0] = v.x; dr[l][j4 * 4 + 1] = v.y;
        dr[l][j4 * 4 + 2] = v.z; dr[l][j4 * 4 + 3] = v.w;
    }
    for (int i = tid; i < 512; i += 256) {
        int dd = i >> 3, j4 = i & 7;
        *reinterpret_cast<float4*>(&wd[dd][j4 * 4]) =
            *reinterpret_cast<const float4*>(Wdt + (size_t)(d0 + dd) * Rr + j4 * 4);
    }
    __syncthreads();

    const int w = tid >> 6, lane = tid & 63;
    float drr[32];
    #pragma unroll
    for (int j = 0; j < 32; ++j) drr[j] = dr[lane][j];

    float xv[16];
    {
        const float* xp = x + (size_t)(b * Lsz + l0 + lane) * Dm + d0 + w * 16;
        #pragma unroll
        for (int q = 0; q < 4; ++q) {
            float4 v = reinterpret_cast<const float4*>(xp)[q];
            xv[q*4] = v.x; xv[q*4+1] = v.y; xv[q*4+2] = v.z; xv[q*4+3] = v.w;
        }
    }

    float dl[16];
    #pragma unroll
    for (int i = 0; i < 16; ++i) {
        int dd = w * 16 + i;
        float z = bdt[d0 + dd];
        const float4* wr = reinterpret_cast<const float4*>(&wd[dd][0]);
        #pragma unroll
        for (int j4 = 0; j4 < 8; ++j4) {
            float4 wv = wr[j4];
            z = fmaf(drr[j4*4+0], wv.x, z);
            z = fmaf(drr[j4*4+1], wv.y, z);
            z = fmaf(drr[j4*4+2], wv.z, z);
            z = fmaf(drr[j4*4+3], wv.w, z);
        }
        dl[i] = (z > 20.f) ? z : log1pf(expf(z));   // stable softplus
    }

    // pass A: delta -> transpose -> coalesced store
    #pragma unroll
    for (int i = 0; i < 16; ++i) pt[w * 16 + i][lane] = dl[i];
    __syncthreads();
    for (int i = tid; i < 4096; i += 256) {
        int dd = i >> 6, ll = i & 63;
        delta_t[((size_t)(b * Dm + d0 + dd)) * Lsz + l0 + ll] = pt[dd][ll];
    }
    __syncthreads();
    // pass B: du = delta * x
    #pragma unroll
    for (int i = 0; i < 16; ++i) pt[w * 16 + i][lane] = dl[i] * xv[i];
    __syncthreads();
    for (int i = tid; i < 4096; i += 256) {
        int dd = i >> 6, ll = i & 63;
        du_t[((size_t)(b * Dm + d0 + dd)) * Lsz + l0 + ll] = pt[dd][ll];
    }
}

// ---------------- K3: sequential scan, one wave per (b,d) channel ----------------
__global__ __launch_bounds__(128) void k3_scan(const float* __restrict__ delta_t,
                                               const float* __restrict__ du_t,
                                               const float* __restrict__ xdbl,
                                               const float* __restrict__ Alog,
                                               float* __restrict__ y_t) {
    __shared__ float part[2][64][65];
    const int lane = threadIdx.x & 63;
    const int w = __builtin_amdgcn_readfirstlane(threadIdx.x >> 6);
    const int chan = blockIdx.x * 2 + w;          // 0..1023
    const int b = chan >> 9, d = chan & 511;
    const float A2 = -expf(Alog[(size_t)d * Nst + lane]) * 1.44269504f; // A*log2(e)
    const size_t cb = (size_t)chan * Lsz;
    float h = 0.f;
    for (int c = 0; c < 32; ++c) {
        const int t0 = c * 64;
        #pragma unroll 16
        for (int j = 0; j < 64; ++j) {
            const int t = t0 + j;
            float dlv = delta_t[cb + t];          // wave-uniform scalar
            float duv = du_t[cb + t];             // wave-uniform scalar
            const float* xdr = xdbl + (size_t)(b * Lsz + t) * Ee;
            float Bv = xdr[Rr + lane];            // coalesced across lanes
            float Cv = xdr[Rr + Nst + lane];
            float a = exp2f(dlv * A2);            // exp(delta*A)
            h = fmaf(a, h, duv * Bv);
            part[w][j][lane] = h * Cv;            // defer reduction
        }
        __syncthreads();
        float ysum = 0.f;
        #pragma unroll 8
        for (int n = 0; n < 64; ++n) ysum += part[w][lane][n];  // row sum, conflict-free
        y_t[cb + t0 + lane] = ysum;               // coalesced y store (b,d,l)
        __syncthreads();
    }
}

// ---------------- K4: out(b,l,d) = y_t(b,d,l)^T + x * D ----------------
__global__ __launch_bounds__(256) void k4_out(const float* __restrict__ y_t,
                                              const float* __restrict__ x,
                                              const float* __restrict__ Dv,
                                              float* __restrict__ out) {
    __shared__ float tl[64][65];
    const int tid = threadIdx.x;
    const int lt = blockIdx.x & 31;
    const int dt = (blockIdx.x >> 5) & 7;
    const int b  = blockIdx.x >> 8;
    const int l0 = lt * 64, d0 = dt * 64;
    for (int i = tid; i < 4096; i += 256) {
        int dd = i >> 6, ll = i & 63;
        tl[dd][ll] = y_t[((size_t)(b * Dm + d0 + dd)) * Lsz + l0 + ll];
    }
    __syncthreads();
    for (int i = tid; i < 4096; i += 256) {
        int ll = i >> 6, dd = i & 63;
        size_t gi = ((size_t)(b * Lsz + l0 + ll)) * Dm + d0 + dd;
        out[gi] = tl[dd][ll] + x[gi] * Dv[d0 + dd];
    }
}

extern "C" void kernel_launch(void* const* d_in, const int* in_sizes, int n_in,
                              void* d_out, int out_size, void* d_ws, size_t ws_size,
                              hipStream_t stream) {
    const float* x    = (const float*)d_in[0];
    const float* Wxp  = (const float*)d_in[1];
    const float* Wdt  = (const float*)d_in[2];
    const float* bdt  = (const float*)d_in[3];
    const float* Alog = (const float*)d_in[4];
    const float* Dv   = (const float*)d_in[5];
    float* out = (float*)d_out;

    char* ws = (char*)d_ws;
    float* xdbl    = (float*)ws;                                  // 4096*160 = 2.62 MB
    float* delta_t = (float*)(ws + (size_t)4096 * Ee * 4);        // 1024*2048 = 8.39 MB
    float* du_t    = delta_t + (size_t)1024 * Lsz;                // 8.39 MB
    float* y_t     = du_t    + (size_t)1024 * Lsz;                // 8.39 MB

    hipLaunchKernelGGL(k1_xproj, dim3(256), dim3(256), 0, stream, x, Wxp, xdbl);
    hipLaunchKernelGGL(k2_delta, dim3(512), dim3(256), 0, stream, xdbl, x, Wdt, bdt, delta_t, du_t);
    hipLaunchKernelGGL(k3_scan,  dim3(512), dim3(128), 0, stream, delta_t, du_t, xdbl, Alog, y_t);
    hipLaunchKernelGGL(k4_out,   dim3(512), dim3(256), 0, stream, y_t, x, Dv, out);
}

// Round 2
// 187.428 us; speedup vs baseline: 1.7448x; 1.7448x over previous
//
#include <hip/hip_runtime.h>
#include <cstdint>

#define Bsz 2
#define Lsz 2048
#define Dm  512
#define Nst 64
#define Rr  32
#define Ee  160   // r + 2n
#define NCHUNK 32
#define CLEN   64

__device__ __forceinline__ float rdlane(float v, int l) {
    return __int_as_float(__builtin_amdgcn_readlane(__float_as_int(v), l));
}

// ---------------- K0: Wt4[k4][e] = float4(W[e][4k4..4k4+3]) ----------------
__global__ __launch_bounds__(256) void k0_wt(const float* __restrict__ W,
                                             float4* __restrict__ Wt4) {
    int gid = blockIdx.x * 256 + threadIdx.x;   // 20480 total
    int k4 = gid & 127, e = gid >> 7;
    float4 v = *reinterpret_cast<const float4*>(W + (size_t)e * Dm + k4 * 4);
    Wt4[k4 * Ee + e] = v;
}

// ---------------- K1: xdbl = x @ W^T via Wt4; lane = e, rows via s_load ----------------
__global__ __launch_bounds__(192) void k1_xproj(const float* __restrict__ x,
                                                const float4* __restrict__ Wt4,
                                                float* __restrict__ xdbl) {
    const int tid = threadIdx.x;
    const int e = (tid < Ee) ? tid : (Ee - 1);
    const int row0 = blockIdx.x * 8;
    float acc[8] = {0.f, 0.f, 0.f, 0.f, 0.f, 0.f, 0.f, 0.f};
    #pragma unroll 2
    for (int k4 = 0; k4 < 128; ++k4) {
        const float4 wv = Wt4[k4 * Ee + e];
        #pragma unroll
        for (int r = 0; r < 8; ++r) {
            const float4 xv = *reinterpret_cast<const float4*>(
                x + (size_t)(row0 + r) * Dm + k4 * 4);   // uniform -> s_load
            acc[r] = fmaf(xv.x, wv.x, acc[r]);
            acc[r] = fmaf(xv.y, wv.y, acc[r]);
            acc[r] = fmaf(xv.z, wv.z, acc[r]);
            acc[r] = fmaf(xv.w, wv.w, acc[r]);
        }
    }
    if (tid < Ee) {
        #pragma unroll
        for (int r = 0; r < 8; ++r)
            xdbl[(size_t)(row0 + r) * Ee + tid] = acc[r];
    }
}

// ------- K2: delta = softplus(delta_r @ W_dt^T + b_dt); store delta_t, du_t (b,d,l) -------
__global__ __launch_bounds__(256) void k2_delta(const float* __restrict__ xdbl,
                                                const float* __restrict__ x,
                                                const float* __restrict__ Wdt,
                                                const float* __restrict__ bdt,
                                                float* __restrict__ delta_t,
                                                float* __restrict__ du_t) {
    __shared__ float dr[64][33];
    __shared__ float wd[64][32];
    __shared__ float pt[64][65];
    const int tid = threadIdx.x;
    const int lt = blockIdx.x & 31;
    const int dt = (blockIdx.x >> 5) & 7;
    const int b  = blockIdx.x >> 8;
    const int l0 = lt * 64, d0 = dt * 64;

    for (int i = tid; i < 512; i += 256) {
        int l = i >> 3, j4 = i & 7;
        const float4 v = *reinterpret_cast<const float4*>(
            xdbl + (size_t)(b * Lsz + l0 + l) * Ee + j4 * 4);
        dr[l][j4 * 4 + 0] = v.x; dr[l][j4 * 4 + 1] = v.y;
        dr[l][j4 * 4 + 2] = v.z; dr[l][j4 * 4 + 3] = v.w;
    }
    for (int i = tid; i < 512; i += 256) {
        int dd = i >> 3, j4 = i & 7;
        *reinterpret_cast<float4*>(&wd[dd][j4 * 4]) =
            *reinterpret_cast<const float4*>(Wdt + (size_t)(d0 + dd) * Rr + j4 * 4);
    }
    __syncthreads();

    const int w = tid >> 6, lane = tid & 63;
    float drr[32];
    #pragma unroll
    for (int j = 0; j < 32; ++j) drr[j] = dr[lane][j];

    float xv[16];
    {
        const float* xp = x + (size_t)(b * Lsz + l0 + lane) * Dm + d0 + w * 16;
        #pragma unroll
        for (int q = 0; q < 4; ++q) {
            float4 v = reinterpret_cast<const float4*>(xp)[q];
            xv[q*4] = v.x; xv[q*4+1] = v.y; xv[q*4+2] = v.z; xv[q*4+3] = v.w;
        }
    }

    float dl[16];
    #pragma unroll
    for (int i = 0; i < 16; ++i) {
        int dd = w * 16 + i;
        float z = bdt[d0 + dd];
        const float4* wr = reinterpret_cast<const float4*>(&wd[dd][0]);
        #pragma unroll
        for (int j4 = 0; j4 < 8; ++j4) {
            float4 wv = wr[j4];
            z = fmaf(drr[j4*4+0], wv.x, z);
            z = fmaf(drr[j4*4+1], wv.y, z);
            z = fmaf(drr[j4*4+2], wv.z, z);
            z = fmaf(drr[j4*4+3], wv.w, z);
        }
        dl[i] = (z > 20.f) ? z : log1pf(expf(z));
    }

    #pragma unroll
    for (int i = 0; i < 16; ++i) pt[w * 16 + i][lane] = dl[i];
    __syncthreads();
    for (int i = tid; i < 4096; i += 256) {
        int dd = i >> 6, ll = i & 63;
        delta_t[((size_t)(b * Dm + d0 + dd)) * Lsz + l0 + ll] = pt[dd][ll];
    }
    __syncthreads();
    #pragma unroll
    for (int i = 0; i < 16; ++i) pt[w * 16 + i][lane] = dl[i] * xv[i];
    __syncthreads();
    for (int i = tid; i < 4096; i += 256) {
        int dd = i >> 6, ll = i & 63;
        du_t[((size_t)(b * Dm + d0 + dd)) * Lsz + l0 + ll] = pt[dd][ll];
    }
}

// ---------------- K3a: local chunk scans (h0 = 0) -> hf, sumdl ----------------
__global__ __launch_bounds__(256) void k3a(const float* __restrict__ delta_t,
                                           const float* __restrict__ du_t,
                                           const float* __restrict__ xdbl,
                                           const float* __restrict__ Alog,
                                           float* __restrict__ hf,
                                           float* __restrict__ sumdl) {
    __shared__ float Bs[64][64];
    const int tid = threadIdx.x;
    const int w = tid >> 6, lane = tid & 63;
    const int c = blockIdx.x & 31;
    const int g = blockIdx.x >> 5;          // 0..255 -> 4 chans (same b)
    const int chan = g * 4 + w;
    const int b = chan >> 9, d = chan & 511;
    const int t0 = c * CLEN;
    const float* xb0 = xdbl + ((size_t)b * Lsz + t0) * Ee;
    for (int i = tid; i < 1024; i += 256) {      // B tile, shared by 4 chans
        int row = i >> 4, q = i & 15;
        float4 v = *reinterpret_cast<const float4*>(xb0 + row * Ee + Rr + q * 4);
        *reinterpret_cast<float4*>(&Bs[row][q * 4]) = v;
    }
    const float A2 = -expf(Alog[(size_t)d * Nst + lane]) * 1.44269504f;
    const size_t cb = (size_t)chan * Lsz;
    float dreg  = delta_t[cb + t0 + lane];
    float dureg = du_t[cb + t0 + lane];
    __syncthreads();
    float h = 0.f;
    #pragma unroll 16
    for (int j = 0; j < CLEN; ++j) {
        float dlv = rdlane(dreg, j);
        float duv = rdlane(dureg, j);
        float a = exp2f(dlv * A2);
        h = fmaf(a, h, duv * Bs[j][lane]);
    }
    float s = dreg;
    s += __shfl_xor(s, 1);  s += __shfl_xor(s, 2);  s += __shfl_xor(s, 4);
    s += __shfl_xor(s, 8);  s += __shfl_xor(s, 16); s += __shfl_xor(s, 32);
    hf[((size_t)chan * NCHUNK + c) * Nst + lane] = h;
    if (lane == 0) sumdl[chan * NCHUNK + c] = s;
}

// ---------------- K3b: sequential fix-up over chunks; hf <- h0 (in place) ----------------
__global__ __launch_bounds__(256) void k3b(const float* __restrict__ Alog,
                                           const float* __restrict__ sumdl,
                                           float* __restrict__ hf) {
    const int tid = threadIdx.x;
    const int w = tid >> 6, lane = tid & 63;
    const int chan = blockIdx.x * 4 + w;
    const int d = chan & 511;
    const float A2 = -expf(Alog[(size_t)d * Nst + lane]) * 1.44269504f;
    const size_t base = (size_t)chan * NCHUNK * Nst + lane;
    float h0 = 0.f, prevhf = 0.f, prevP = 0.f;
    #pragma unroll 4
    for (int c = 0; c < NCHUNK; ++c) {
        float curhf = hf[base + c * Nst];
        float curP  = exp2f(A2 * sumdl[chan * NCHUNK + c]);
        h0 = (c == 0) ? 0.f : fmaf(prevP, h0, prevhf);
        hf[base + c * Nst] = h0;
        prevhf = curhf; prevP = curP;
    }
}

// ---------------- K3c: chunk scans from h0, emit y (b,d,l) ----------------
__global__ __launch_bounds__(256) void k3c(const float* __restrict__ delta_t,
                                           const float* __restrict__ du_t,
                                           const float* __restrict__ xdbl,
                                           const float* __restrict__ Alog,
                                           const float* __restrict__ h0s,
                                           float* __restrict__ y_t) {
    __shared__ float BC[64][128];       // B | C, shared by 4 chans
    __shared__ float part[4][16][65];   // per-wave transpose buffer
    const int tid = threadIdx.x;
    const int w = tid >> 6, lane = tid & 63;
    const int c = blockIdx.x & 31;
    const int g = blockIdx.x >> 5;
    const int chan = g * 4 + w;
    const int b = chan >> 9, d = chan & 511;
    const int t0 = c * CLEN;
    const float* xb0 = xdbl + ((size_t)b * Lsz + t0) * Ee;
    for (int i = tid; i < 2048; i += 256) {
        int row = i >> 5, q = i & 31;
        float4 v = *reinterpret_cast<const float4*>(xb0 + row * Ee + Rr + q * 4);
        *reinterpret_cast<float4*>(&BC[row][q * 4]) = v;
    }
    const float A2 = -expf(Alog[(size_t)d * Nst + lane]) * 1.44269504f;
    const size_t cb = (size_t)chan * Lsz;
    float dreg  = delta_t[cb + t0 + lane];
    float dureg = du_t[cb + t0 + lane];
    float h = h0s[((size_t)chan * NCHUNK + c) * Nst + lane];
    __syncthreads();
    #pragma unroll
    for (int s4 = 0; s4 < 4; ++s4) {
        #pragma unroll
        for (int j = 0; j < 16; ++j) {
            const int jj = s4 * 16 + j;
            float dlv = rdlane(dreg, jj);
            float duv = rdlane(dureg, jj);
            float a = exp2f(dlv * A2);
            h = fmaf(a, h, duv * BC[jj][lane]);
            part[w][j][lane] = h * BC[jj][64 + lane];   // wave-private
        }
        float v = 0.f;
        const int r = lane & 15, seg = lane >> 4;
        #pragma unroll
        for (int q = 0; q < 16; ++q) v += part[w][r][seg * 16 + q];
        v += __shfl_xor(v, 16);
        v += __shfl_xor(v, 32);
        if (lane < 16) y_t[cb + t0 + s4 * 16 + lane] = v;
    }
}

// ---------------- K4: out(b,l,d) = y_t(b,d,l)^T + x * D ----------------
__global__ __launch_bounds__(256) void k4_out(const float* __restrict__ y_t,
                                              const float* __restrict__ x,
                                              const float* __restrict__ Dv,
                                              float* __restrict__ out) {
    __shared__ float tl[64][65];
    const int tid = threadIdx.x;
    const int lt = blockIdx.x & 31;
    const int dt = (blockIdx.x >> 5) & 7;
    const int b  = blockIdx.x >> 8;
    const int l0 = lt * 64, d0 = dt * 64;
    for (int i = tid; i < 4096; i += 256) {
        int dd = i >> 6, ll = i & 63;
        tl[dd][ll] = y_t[((size_t)(b * Dm + d0 + dd)) * Lsz + l0 + ll];
    }
    __syncthreads();
    for (int i = tid; i < 4096; i += 256) {
        int ll = i >> 6, dd = i & 63;
        size_t gi = ((size_t)(b * Lsz + l0 + ll)) * Dm + d0 + dd;
        out[gi] = tl[dd][ll] + x[gi] * Dv[d0 + dd];
    }
}

extern "C" void kernel_launch(void* const* d_in, const int* in_sizes, int n_in,
                              void* d_out, int out_size, void* d_ws, size_t ws_size,
                              hipStream_t stream) {
    const float* x    = (const float*)d_in[0];
    const float* Wxp  = (const float*)d_in[1];
    const float* Wdt  = (const float*)d_in[2];
    const float* bdt  = (const float*)d_in[3];
    const float* Alog = (const float*)d_in[4];
    const float* Dv   = (const float*)d_in[5];
    float* out = (float*)d_out;

    float* ws = (float*)d_ws;
    float*  xdbl    = ws;                                   // 655,360
    float4* Wt4     = (float4*)(ws + 655360);               // 81,920 floats
    float*  delta_t = ws + 737280;                          // 2,097,152
    float*  du_t    = ws + 2834432;                         // 2,097,152
    float*  y_t     = ws + 4931584;                         // 2,097,152
    float*  hf      = ws + 7028736;                         // 2,097,152
    float*  sumdl   = ws + 9125888;                         // 32,768

    hipLaunchKernelGGL(k0_wt,    dim3(80),   dim3(256), 0, stream, Wxp, Wt4);
    hipLaunchKernelGGL(k1_xproj, dim3(512),  dim3(192), 0, stream, x, Wt4, xdbl);
    hipLaunchKernelGGL(k2_delta, dim3(512),  dim3(256), 0, stream, xdbl, x, Wdt, bdt, delta_t, du_t);
    hipLaunchKernelGGL(k3a,      dim3(8192), dim3(256), 0, stream, delta_t, du_t, xdbl, Alog, hf, sumdl);
    hipLaunchKernelGGL(k3b,      dim3(256),  dim3(256), 0, stream, Alog, sumdl, hf);
    hipLaunchKernelGGL(k3c,      dim3(8192), dim3(256), 0, stream, delta_t, du_t, xdbl, Alog, hf, y_t);
    hipLaunchKernelGGL(k4_out,   dim3(512),  dim3(256), 0, stream, y_t, x, Dv, out);
}

// Round 3
// 180.324 us; speedup vs baseline: 1.8135x; 1.0394x over previous
//
#include <hip/hip_runtime.h>
#include <cstdint>

#define Bsz 2
#define Lsz 2048
#define Dm  512
#define Nst 64
#define Rr  32
#define Ee  160   // r + 2n
#define NCHUNK 32
#define CLEN   64

// ---------------- K0: Wt4[k4][e] = float4(W[e][4k4..4k4+3]) ----------------
__global__ __launch_bounds__(256) void k0_wt(const float* __restrict__ W,
                                             float4* __restrict__ Wt4) {
    int gid = blockIdx.x * 256 + threadIdx.x;   // 20480 total
    int k4 = gid & 127, e = gid >> 7;
    float4 v = *reinterpret_cast<const float4*>(W + (size_t)e * Dm + k4 * 4);
    Wt4[k4 * Ee + e] = v;
}

// ---------------- K1: xdbl = x @ W^T via Wt4; lane = e, rows via s_load ----------------
__global__ __launch_bounds__(192) void k1_xproj(const float* __restrict__ x,
                                                const float4* __restrict__ Wt4,
                                                float* __restrict__ xdbl) {
    const int tid = threadIdx.x;
    const int e = (tid < Ee) ? tid : (Ee - 1);
    const int row0 = blockIdx.x * 8;
    float acc[8] = {0.f, 0.f, 0.f, 0.f, 0.f, 0.f, 0.f, 0.f};
    #pragma unroll 2
    for (int k4 = 0; k4 < 128; ++k4) {
        const float4 wv = Wt4[k4 * Ee + e];
        #pragma unroll
        for (int r = 0; r < 8; ++r) {
            const float4 xv = *reinterpret_cast<const float4*>(
                x + (size_t)(row0 + r) * Dm + k4 * 4);   // uniform -> s_load
            acc[r] = fmaf(xv.x, wv.x, acc[r]);
            acc[r] = fmaf(xv.y, wv.y, acc[r]);
            acc[r] = fmaf(xv.z, wv.z, acc[r]);
            acc[r] = fmaf(xv.w, wv.w, acc[r]);
        }
    }
    if (tid < Ee) {
        #pragma unroll
        for (int r = 0; r < 8; ++r)
            xdbl[(size_t)(row0 + r) * Ee + tid] = acc[r];
    }
}

// ------- K2: delta = softplus(delta_r @ W_dt^T + b_dt); store delta_t, du_t (b,d,l);
//             also sumdl[chan][chunk] = sum of delta over the 64-step chunk -------
__global__ __launch_bounds__(256) void k2_delta(const float* __restrict__ xdbl,
                                                const float* __restrict__ x,
                                                const float* __restrict__ Wdt,
                                                const float* __restrict__ bdt,
                                                float* __restrict__ delta_t,
                                                float* __restrict__ du_t,
                                                float* __restrict__ sumdl) {
    __shared__ float dr[64][33];
    __shared__ float wd[64][32];
    __shared__ float pt[64][65];
    const int tid = threadIdx.x;
    const int lt = blockIdx.x & 31;
    const int dt = (blockIdx.x >> 5) & 7;
    const int b  = blockIdx.x >> 8;
    const int l0 = lt * 64, d0 = dt * 64;

    for (int i = tid; i < 512; i += 256) {
        int l = i >> 3, j4 = i & 7;
        const float4 v = *reinterpret_cast<const float4*>(
            xdbl + (size_t)(b * Lsz + l0 + l) * Ee + j4 * 4);
        dr[l][j4 * 4 + 0] = v.x; dr[l][j4 * 4 + 1] = v.y;
        dr[l][j4 * 4 + 2] = v.z; dr[l][j4 * 4 + 3] = v.w;
    }
    for (int i = tid; i < 512; i += 256) {
        int dd = i >> 3, j4 = i & 7;
        *reinterpret_cast<float4*>(&wd[dd][j4 * 4]) =
            *reinterpret_cast<const float4*>(Wdt + (size_t)(d0 + dd) * Rr + j4 * 4);
    }
    __syncthreads();

    const int w = tid >> 6, lane = tid & 63;
    float drr[32];
    #pragma unroll
    for (int j = 0; j < 32; ++j) drr[j] = dr[lane][j];

    float xv[16];
    {
        const float* xp = x + (size_t)(b * Lsz + l0 + lane) * Dm + d0 + w * 16;
        #pragma unroll
        for (int q = 0; q < 4; ++q) {
            float4 v = reinterpret_cast<const float4*>(xp)[q];
            xv[q*4] = v.x; xv[q*4+1] = v.y; xv[q*4+2] = v.z; xv[q*4+3] = v.w;
        }
    }

    float dl[16];
    #pragma unroll
    for (int i = 0; i < 16; ++i) {
        int dd = w * 16 + i;
        float z = bdt[d0 + dd];
        const float4* wr = reinterpret_cast<const float4*>(&wd[dd][0]);
        #pragma unroll
        for (int j4 = 0; j4 < 8; ++j4) {
            float4 wv = wr[j4];
            z = fmaf(drr[j4*4+0], wv.x, z);
            z = fmaf(drr[j4*4+1], wv.y, z);
            z = fmaf(drr[j4*4+2], wv.z, z);
            z = fmaf(drr[j4*4+3], wv.w, z);
        }
        dl[i] = (z > 20.f) ? z : log1pf(expf(z));
    }

    #pragma unroll
    for (int i = 0; i < 16; ++i) pt[w * 16 + i][lane] = dl[i];
    __syncthreads();
    for (int i = tid; i < 4096; i += 256) {
        int dd = i >> 6, ll = i & 63;
        delta_t[((size_t)(b * Dm + d0 + dd)) * Lsz + l0 + ll] = pt[dd][ll];
    }
    if (tid < 64) {                       // chunk-sum of delta for channel d0+tid
        float s = 0.f;
        #pragma unroll 16
        for (int q = 0; q < 64; ++q) s += pt[tid][q];
        sumdl[(size_t)(b * Dm + d0 + tid) * NCHUNK + lt] = s;
    }
    __syncthreads();
    #pragma unroll
    for (int i = 0; i < 16; ++i) pt[w * 16 + i][lane] = dl[i] * xv[i];
    __syncthreads();
    for (int i = tid; i < 4096; i += 256) {
        int dd = i >> 6, ll = i & 63;
        du_t[((size_t)(b * Dm + d0 + dd)) * Lsz + l0 + ll] = pt[dd][ll];
    }
}

// ---------------- K3a: local chunk scans (h0 = 0) -> hf; 4 chans/wave ----------------
__global__ __launch_bounds__(256) void k3a(const float* __restrict__ delta_t,
                                           const float* __restrict__ du_t,
                                           const float* __restrict__ xdbl,
                                           const float* __restrict__ Alog,
                                           float* __restrict__ hf) {
    __shared__ float Bs[64][64];
    const int tid = threadIdx.x;
    const int w = __builtin_amdgcn_readfirstlane(tid >> 6);
    const int lane = tid & 63;
    const int c   = blockIdx.x >> 6;          // chunk
    const int grp = blockIdx.x & 63;          // chan-group of 16
    const int chan = grp * 16 + w * 4;        // uniform base chan
    const int b = chan >> 9;
    const int t0 = c * CLEN;
    const float* __restrict__ xb0 = xdbl + ((size_t)b * Lsz + t0) * Ee;
    for (int i = tid; i < 1024; i += 256) {
        int row = i >> 4, q = i & 15;
        float4 v = *reinterpret_cast<const float4*>(xb0 + row * Ee + Rr + q * 4);
        *reinterpret_cast<float4*>(&Bs[row][q * 4]) = v;
    }
    float A2[4], h[4];
    const float* dp[4]; const float* up[4];
    #pragma unroll
    for (int ch = 0; ch < 4; ++ch) {
        int d = (chan + ch) & 511;
        A2[ch] = -expf(Alog[(size_t)d * Nst + lane]) * 1.44269504f;
        dp[ch] = delta_t + (size_t)(chan + ch) * Lsz + t0;
        up[ch] = du_t    + (size_t)(chan + ch) * Lsz + t0;
        h[ch] = 0.f;
    }
    __syncthreads();
    #pragma unroll 8
    for (int j = 0; j < CLEN; ++j) {
        float Bv = Bs[j][lane];
        #pragma unroll
        for (int ch = 0; ch < 4; ++ch) {
            float a = exp2f(dp[ch][j] * A2[ch]);   // dp/up are s_loads
            h[ch] = fmaf(a, h[ch], up[ch][j] * Bv);
        }
    }
    #pragma unroll
    for (int ch = 0; ch < 4; ++ch)
        hf[((size_t)(chan + ch) * NCHUNK + c) * Nst + lane] = h[ch];
}

// ---------------- K3b: sequential fix-up over chunks; hf <- h0 (in place) ----------------
__global__ __launch_bounds__(256) void k3b(const float* __restrict__ Alog,
                                           const float* __restrict__ sumdl,
                                           float* __restrict__ hf) {
    const int tid = threadIdx.x;
    const int w = tid >> 6, lane = tid & 63;
    const int chan = blockIdx.x * 4 + w;
    const int d = chan & 511;
    const float A2 = -expf(Alog[(size_t)d * Nst + lane]) * 1.44269504f;
    const size_t base = (size_t)chan * NCHUNK * Nst + lane;
    float h0 = 0.f, prevhf = 0.f, prevP = 0.f;
    #pragma unroll 4
    for (int c = 0; c < NCHUNK; ++c) {
        float curhf = hf[base + c * Nst];
        float curP  = exp2f(A2 * sumdl[chan * NCHUNK + c]);
        h0 = (c == 0) ? 0.f : fmaf(prevP, h0, prevhf);
        hf[base + c * Nst] = h0;
        prevhf = curhf; prevP = curP;
    }
}

// ---------------- K3c: chunk scans from h0, emit y (b,d,l); 4 chans/wave ----------------
__global__ __launch_bounds__(256) void k3c(const float* __restrict__ delta_t,
                                           const float* __restrict__ du_t,
                                           const float* __restrict__ xdbl,
                                           const float* __restrict__ Alog,
                                           const float* __restrict__ h0s,
                                           float* __restrict__ y_t) {
    __shared__ float BC[64][128];        // B | C, shared by 16 chans
    __shared__ float part[4][16][65];    // per-wave: 16 rows = 4 chans x 4 steps
    __shared__ float ystage[4][4][66];   // per-wave y staging
    const int tid = threadIdx.x;
    const int w = __builtin_amdgcn_readfirstlane(tid >> 6);
    const int lane = tid & 63;
    const int c   = blockIdx.x >> 6;
    const int grp = blockIdx.x & 63;
    const int chan = grp * 16 + w * 4;
    const int b = chan >> 9;
    const int t0 = c * CLEN;
    const float* __restrict__ xb0 = xdbl + ((size_t)b * Lsz + t0) * Ee;
    for (int i = tid; i < 2048; i += 256) {
        int row = i >> 5, q = i & 31;
        float4 v = *reinterpret_cast<const float4*>(xb0 + row * Ee + Rr + q * 4);
        *reinterpret_cast<float4*>(&BC[row][q * 4]) = v;
    }
    float A2[4], h[4];
    const float* dp[4]; const float* up[4];
    #pragma unroll
    for (int ch = 0; ch < 4; ++ch) {
        int d = (chan + ch) & 511;
        A2[ch] = -expf(Alog[(size_t)d * Nst + lane]) * 1.44269504f;
        dp[ch] = delta_t + (size_t)(chan + ch) * Lsz + t0;
        up[ch] = du_t    + (size_t)(chan + ch) * Lsz + t0;
        h[ch] = h0s[((size_t)(chan + ch) * NCHUNK + c) * Nst + lane];
    }
    __syncthreads();
    const int r = lane & 15, seg = lane >> 4;
    #pragma unroll 4
    for (int g4 = 0; g4 < 16; ++g4) {
        #pragma unroll
        for (int j = 0; j < 4; ++j) {
            const int t = g4 * 4 + j;
            float Bv = BC[t][lane];
            float Cv = BC[t][64 + lane];
            #pragma unroll
            for (int ch = 0; ch < 4; ++ch) {
                float a = exp2f(dp[ch][t] * A2[ch]);     // s_load operands
                h[ch] = fmaf(a, h[ch], up[ch][t] * Bv);
                part[w][ch * 4 + j][lane] = h[ch] * Cv;  // wave-private
            }
        }
        float v = 0.f;
        #pragma unroll
        for (int q = 0; q < 16; ++q) v += part[w][r][seg * 16 + q];
        v += __shfl_xor(v, 16);
        v += __shfl_xor(v, 32);
        if (lane < 16) ystage[w][lane >> 2][g4 * 4 + (lane & 3)] = v;
    }
    #pragma unroll
    for (int ch = 0; ch < 4; ++ch)
        y_t[(size_t)(chan + ch) * Lsz + t0 + lane] = ystage[w][ch][lane];
}

// ---------------- K4: out(b,l,d) = y_t(b,d,l)^T + x * D ----------------
__global__ __launch_bounds__(256) void k4_out(const float* __restrict__ y_t,
                                              const float* __restrict__ x,
                                              const float* __restrict__ Dv,
                                              float* __restrict__ out) {
    __shared__ float tl[64][65];
    const int tid = threadIdx.x;
    const int lt = blockIdx.x & 31;
    const int dt = (blockIdx.x >> 5) & 7;
    const int b  = blockIdx.x >> 8;
    const int l0 = lt * 64, d0 = dt * 64;
    for (int i = tid; i < 4096; i += 256) {
        int dd = i >> 6, ll = i & 63;
        tl[dd][ll] = y_t[((size_t)(b * Dm + d0 + dd)) * Lsz + l0 + ll];
    }
    __syncthreads();
    for (int i = tid; i < 4096; i += 256) {
        int ll = i >> 6, dd = i & 63;
        size_t gi = ((size_t)(b * Lsz + l0 + ll)) * Dm + d0 + dd;
        out[gi] = tl[dd][ll] + x[gi] * Dv[d0 + dd];
    }
}

extern "C" void kernel_launch(void* const* d_in, const int* in_sizes, int n_in,
                              void* d_out, int out_size, void* d_ws, size_t ws_size,
                              hipStream_t stream) {
    const float* x    = (const float*)d_in[0];
    const float* Wxp  = (const float*)d_in[1];
    const float* Wdt  = (const float*)d_in[2];
    const float* bdt  = (const float*)d_in[3];
    const float* Alog = (const float*)d_in[4];
    const float* Dv   = (const float*)d_in[5];
    float* out = (float*)d_out;

    float* ws = (float*)d_ws;
    float*  xdbl    = ws;                                   // 655,360
    float4* Wt4     = (float4*)(ws + 655360);               // 81,920 floats
    float*  delta_t = ws + 737280;                          // 2,097,152
    float*  du_t    = ws + 2834432;                         // 2,097,152
    float*  y_t     = ws + 4931584;                         // 2,097,152
    float*  hf      = ws + 7028736;                         // 2,097,152
    float*  sumdl   = ws + 9125888;                         // 32,768

    hipLaunchKernelGGL(k0_wt,    dim3(80),   dim3(256), 0, stream, Wxp, Wt4);
    hipLaunchKernelGGL(k1_xproj, dim3(512),  dim3(192), 0, stream, x, Wt4, xdbl);
    hipLaunchKernelGGL(k2_delta, dim3(512),  dim3(256), 0, stream, xdbl, x, Wdt, bdt, delta_t, du_t, sumdl);
    hipLaunchKernelGGL(k3a,      dim3(2048), dim3(256), 0, stream, delta_t, du_t, xdbl, Alog, hf);
    hipLaunchKernelGGL(k3b,      dim3(256),  dim3(256), 0, stream, Alog, sumdl, hf);
    hipLaunchKernelGGL(k3c,      dim3(2048), dim3(256), 0, stream, delta_t, du_t, xdbl, Alog, hf, y_t);
    hipLaunchKernelGGL(k4_out,   dim3(512),  dim3(256), 0, stream, y_t, x, Dv, out);
}